// Round 5
// baseline (55.206 us; speedup 1.0000x reference)
//
#include <hip/hip_runtime.h>

#define HWE 131072   // 256*512 env pixels
#define OPIX 16384   // 128*128 output pixels

typedef float f32x2 __attribute__((ext_vector_type(2)));

// Pack per env pixel (fp8 e4m3, HW convert): [x0.rgb, y0.rgb, d1.rgb, d2.rgb,
// d3.rgb, pad] = 16 bytes. env total = 2 MB -> solidly L2-resident.
__global__ __launch_bounds__(256) void k_repack1(
    const float* __restrict__ x, const float* __restrict__ y,
    uint4* __restrict__ env, unsigned* __restrict__ cnt) {
  int px = blockIdx.x * 256 + threadIdx.x;
  if (blockIdx.x == 0 && threadIdx.x == 0) *cnt = 0;  // arm last-block counter
  float o[16];
  #pragma unroll
  for (int c = 0; c < 3; c++) {
    float x0 = __builtin_nontemporal_load(&x[(size_t)px * 3 + c]);
    float y0 = __builtin_nontemporal_load(&y[(size_t)px * 3 + c]);
    o[c]     = x0;
    o[3 + c] = y0;
    #pragma unroll
    for (int b = 1; b < 4; b++) {
      float xv = __builtin_nontemporal_load(&x[((size_t)b * HWE + px) * 3 + c]);
      float yv = __builtin_nontemporal_load(&y[((size_t)b * HWE + px) * 3 + c]);
      o[3 + b * 3 + c] = xv - yv;
    }
  }
  o[15] = 0.f;
  uint4 q;
  q.x = (unsigned)__builtin_amdgcn_cvt_pk_fp8_f32(o[2],  o[3],
        __builtin_amdgcn_cvt_pk_fp8_f32(o[0],  o[1],  0, false), true);
  q.y = (unsigned)__builtin_amdgcn_cvt_pk_fp8_f32(o[6],  o[7],
        __builtin_amdgcn_cvt_pk_fp8_f32(o[4],  o[5],  0, false), true);
  q.z = (unsigned)__builtin_amdgcn_cvt_pk_fp8_f32(o[10], o[11],
        __builtin_amdgcn_cvt_pk_fp8_f32(o[8],  o[9],  0, false), true);
  q.w = (unsigned)__builtin_amdgcn_cvt_pk_fp8_f32(o[14], o[15],
        __builtin_amdgcn_cvt_pk_fp8_f32(o[12], o[13], 0, false), true);
  env[px] = q;
}

// Fused render + cross-group reduce + outputs + loss (last block finishes).
// Block = 512 threads = 32 groups x 16 px; 2 n's per thread. Grid = 1024.
// -> 8192 waves (32/CU with 64-VGPR cap + 34 KB LDS = 4 blocks/CU).
#define SLAB 260           // 16*16 + 4 pad words
__global__ __launch_bounds__(512, 8) void k_render_fused(
    const float* __restrict__ bs0, const float* __restrict__ bd0,
    const int* __restrict__ ix0, const int* __restrict__ iy0,
    const float* __restrict__ w0,
    const float* __restrict__ bs1, const float* __restrict__ bd1,
    const int* __restrict__ ix1, const int* __restrict__ iy1,
    const float* __restrict__ w1,
    const uint4* __restrict__ env, float* __restrict__ d_out,
    float* __restrict__ loss_part, unsigned* __restrict__ cnt) {
  int tid = threadIdx.x;
  int g = tid >> 4;          // 0..31
  int opl = tid & 15;
  int opix = blockIdx.x * 16 + opl;

  const float* bs; const float* bd; const int* ix; const int* iy; const float* w;
  if (g < 16) { bs = bs0; bd = bd0; ix = ix0; iy = iy0; w = w0; }
  else        { bs = bs1; bd = bd1; ix = ix1; iy = iy1; w = w1; }
  int n0 = (g & 15) * 2;

  float acc[15];
  #pragma unroll
  for (int j = 0; j < 15; j++) acc[j] = 0.f;

  #pragma unroll
  for (int k = 0; k < 2; k++) {
    int n = n0 + k;
    int off = n * OPIX + opix;
    float coef = (bd[off] + 10.0f * bs[off]) * w[n];
    int gp = iy[off] * 512 + ix[off];
    uint4 q = env[gp];
    f32x2 v;
    v = __builtin_amdgcn_cvt_pk_f32_fp8(q.x, false); acc[0]  = fmaf(coef, v.x, acc[0]);  acc[1]  = fmaf(coef, v.y, acc[1]);
    v = __builtin_amdgcn_cvt_pk_f32_fp8(q.x, true);  acc[2]  = fmaf(coef, v.x, acc[2]);  acc[3]  = fmaf(coef, v.y, acc[3]);
    v = __builtin_amdgcn_cvt_pk_f32_fp8(q.y, false); acc[4]  = fmaf(coef, v.x, acc[4]);  acc[5]  = fmaf(coef, v.y, acc[5]);
    v = __builtin_amdgcn_cvt_pk_f32_fp8(q.y, true);  acc[6]  = fmaf(coef, v.x, acc[6]);  acc[7]  = fmaf(coef, v.y, acc[7]);
    v = __builtin_amdgcn_cvt_pk_f32_fp8(q.z, false); acc[8]  = fmaf(coef, v.x, acc[8]);  acc[9]  = fmaf(coef, v.y, acc[9]);
    v = __builtin_amdgcn_cvt_pk_f32_fp8(q.z, true);  acc[10] = fmaf(coef, v.x, acc[10]); acc[11] = fmaf(coef, v.y, acc[11]);
    v = __builtin_amdgcn_cvt_pk_f32_fp8(q.w, false); acc[12] = fmaf(coef, v.x, acc[12]); acc[13] = fmaf(coef, v.y, acc[13]);
    v = __builtin_amdgcn_cvt_pk_f32_fp8(q.w, true);  acc[14] = fmaf(coef, v.x, acc[14]);
  }

  __shared__ float sm[32 * SLAB];    // 33.3 KB
  __shared__ float fin[16 * 17];
  __shared__ int is_last;
  {
    float4* my = (float4*)&sm[g * SLAB + opl * 16];
    my[0] = make_float4(acc[0],  acc[1],  acc[2],  acc[3]);
    my[1] = make_float4(acc[4],  acc[5],  acc[6],  acc[7]);
    my[2] = make_float4(acc[8],  acc[9],  acc[10], acc[11]);
    my[3] = make_float4(acc[12], acc[13], acc[14], 0.f);
  }
  __syncthreads();

  // cross-group sum: 256 threads -> (px = tid>>4, component tid&15)
  if (tid < 256) {
    int px = tid >> 4;
    int cp = tid & 15;
    float s = 0.f;
    #pragma unroll
    for (int g2 = 0; g2 < 32; g2++)
      s += sm[g2 * SLAB + px * 16 + cp];
    fin[px * 17 + cp] = s;
  }
  __syncthreads();

  if (tid < 16) {
    float a[15];
    #pragma unroll
    for (int c = 0; c < 15; c++) a[c] = fin[tid * 17 + c];
    int op = blockIdx.x * 16 + tid;
    float l = 0.f;
    #pragma unroll
    for (int c = 0; c < 3; c++) {
      d_out[1 + c * OPIX + op]       = a[c];       // pred[0]
      d_out[1 + (3 + c) * OPIX + op] = a[3 + c];   // gt[0]
      float d0 = a[c] - a[3 + c];
      l += d0 * d0 + a[6 + c] * a[6 + c] + a[9 + c] * a[9 + c]
         + a[12 + c] * a[12 + c];
    }
    #pragma unroll
    for (int s = 8; s > 0; s >>= 1) l += __shfl_down(l, s, 16);
    if (tid == 0) loss_part[blockIdx.x] = l;
  }

  // last-block-done: final deterministic loss reduction, counter self-reset
  if (tid == 0) {
    __threadfence();
    unsigned old = atomicAdd(cnt, 1u);
    is_last = (old == gridDim.x - 1) ? 1 : 0;
  }
  __syncthreads();
  if (is_last) {
    if (tid == 0) *cnt = 0;
    __threadfence();
    float v = loss_part[tid] + loss_part[tid + 512];
    #pragma unroll
    for (int s = 32; s > 0; s >>= 1) v += __shfl_down(v, s, 64);
    __shared__ float red[8];
    int lane = tid & 63, wid = tid >> 6;
    if (lane == 0) red[wid] = v;
    __syncthreads();
    if (tid == 0) {
      float t = 0.f;
      #pragma unroll
      for (int i = 0; i < 8; i++) t += red[i];
      d_out[0] = t * (1.0f / 98304.0f);
    }
  }
}

extern "C" void kernel_launch(void* const* d_in, const int* in_sizes, int n_in,
                              void* d_out, int out_size, void* d_ws, size_t ws_size,
                              hipStream_t stream) {
  const float* x   = (const float*)d_in[0];
  const float* y   = (const float*)d_in[1];
  const float* bs0 = (const float*)d_in[2];
  const float* bd0 = (const float*)d_in[3];
  const int*   ix0 = (const int*)  d_in[4];
  const int*   iy0 = (const int*)  d_in[5];
  const float* w0  = (const float*)d_in[6];
  const float* bs1 = (const float*)d_in[7];
  const float* bd1 = (const float*)d_in[8];
  const int*   ix1 = (const int*)  d_in[9];
  const int*   iy1 = (const int*)  d_in[10];
  const float* w1  = (const float*)d_in[11];
  float* out = (float*)d_out;

  uint4*    env       = (uint4*)d_ws;                               // 2 MB
  float*    loss_part = (float*)((char*)d_ws + (size_t)HWE * 16);   // 1024 f32
  unsigned* cnt       = (unsigned*)(loss_part + 1024);

  hipLaunchKernelGGL(k_repack1, dim3(HWE / 256), dim3(256), 0, stream,
                     x, y, env, cnt);
  hipLaunchKernelGGL(k_render_fused, dim3(OPIX / 16), dim3(512), 0, stream,
                     bs0, bd0, ix0, iy0, w0, bs1, bd1, ix1, iy1, w1,
                     env, out, loss_part, cnt);
}

// Round 6
// 33.886 us; speedup vs baseline: 1.6291x; 1.6291x over previous
//
#include <hip/hip_runtime.h>

#define HWE 131072   // 256*512 env pixels
#define OPIX 16384   // 128*128 output pixels

typedef float f32x2 __attribute__((ext_vector_type(2)));

// Pack per env pixel (fp8 e4m3, HW convert): [x0.rgb, y0.rgb, d1.rgb, d2.rgb,
// d3.rgb, pad] = 16 bytes. env total = 2 MB -> solidly L2-resident.
__global__ __launch_bounds__(256) void k_repack1(
    const float* __restrict__ x, const float* __restrict__ y,
    uint4* __restrict__ env, unsigned* __restrict__ cnt) {
  int px = blockIdx.x * 256 + threadIdx.x;
  if (blockIdx.x == 0 && threadIdx.x == 0) *cnt = 0;  // arm last-block counter
  float o[16];
  #pragma unroll
  for (int c = 0; c < 3; c++) {
    float x0 = __builtin_nontemporal_load(&x[(size_t)px * 3 + c]);
    float y0 = __builtin_nontemporal_load(&y[(size_t)px * 3 + c]);
    o[c]     = x0;
    o[3 + c] = y0;
    #pragma unroll
    for (int b = 1; b < 4; b++) {
      float xv = __builtin_nontemporal_load(&x[((size_t)b * HWE + px) * 3 + c]);
      float yv = __builtin_nontemporal_load(&y[((size_t)b * HWE + px) * 3 + c]);
      o[3 + b * 3 + c] = xv - yv;
    }
  }
  o[15] = 0.f;
  uint4 q;
  q.x = (unsigned)__builtin_amdgcn_cvt_pk_fp8_f32(o[2],  o[3],
        __builtin_amdgcn_cvt_pk_fp8_f32(o[0],  o[1],  0, false), true);
  q.y = (unsigned)__builtin_amdgcn_cvt_pk_fp8_f32(o[6],  o[7],
        __builtin_amdgcn_cvt_pk_fp8_f32(o[4],  o[5],  0, false), true);
  q.z = (unsigned)__builtin_amdgcn_cvt_pk_fp8_f32(o[10], o[11],
        __builtin_amdgcn_cvt_pk_fp8_f32(o[8],  o[9],  0, false), true);
  q.w = (unsigned)__builtin_amdgcn_cvt_pk_fp8_f32(o[14], o[15],
        __builtin_amdgcn_cvt_pk_fp8_f32(o[12], o[13], 0, false), true);
  env[px] = q;
}

// Fused render + cross-group reduce + outputs + loss (last block finishes).
// Round-4 geometry: block = 512 threads = 16 groups x 32 px; 4 n's per thread.
// Grid = OPIX/32 = 512. NO min-waves launch_bounds clause (round-5 spill bug).
#define SLAB 544           // 32 px * 17 floats: stride 17 coprime 32 banks
__global__ __launch_bounds__(512) void k_render_fused(
    const float* __restrict__ bs0, const float* __restrict__ bd0,
    const int* __restrict__ ix0, const int* __restrict__ iy0,
    const float* __restrict__ w0,
    const float* __restrict__ bs1, const float* __restrict__ bd1,
    const int* __restrict__ ix1, const int* __restrict__ iy1,
    const float* __restrict__ w1,
    const uint4* __restrict__ env, float* __restrict__ d_out,
    float* __restrict__ loss_part, unsigned* __restrict__ cnt) {
  int tid = threadIdx.x;
  int g = tid >> 5;          // 0..15
  int opl = tid & 31;
  int opix = blockIdx.x * 32 + opl;

  const float* bs; const float* bd; const int* ix; const int* iy; const float* w;
  if (g < 8) { bs = bs0; bd = bd0; ix = ix0; iy = iy0; w = w0; }
  else       { bs = bs1; bd = bd1; ix = ix1; iy = iy1; w = w1; }
  int n0 = (g & 7) * 4;

  float acc[15];
  #pragma unroll
  for (int j = 0; j < 15; j++) acc[j] = 0.f;

  #pragma unroll
  for (int k = 0; k < 4; k++) {
    int n = n0 + k;
    int off = n * OPIX + opix;
    float coef = (bd[off] + 10.0f * bs[off]) * w[n];
    int gp = iy[off] * 512 + ix[off];
    uint4 q = env[gp];
    f32x2 v;
    v = __builtin_amdgcn_cvt_pk_f32_fp8(q.x, false); acc[0]  = fmaf(coef, v.x, acc[0]);  acc[1]  = fmaf(coef, v.y, acc[1]);
    v = __builtin_amdgcn_cvt_pk_f32_fp8(q.x, true);  acc[2]  = fmaf(coef, v.x, acc[2]);  acc[3]  = fmaf(coef, v.y, acc[3]);
    v = __builtin_amdgcn_cvt_pk_f32_fp8(q.y, false); acc[4]  = fmaf(coef, v.x, acc[4]);  acc[5]  = fmaf(coef, v.y, acc[5]);
    v = __builtin_amdgcn_cvt_pk_f32_fp8(q.y, true);  acc[6]  = fmaf(coef, v.x, acc[6]);  acc[7]  = fmaf(coef, v.y, acc[7]);
    v = __builtin_amdgcn_cvt_pk_f32_fp8(q.z, false); acc[8]  = fmaf(coef, v.x, acc[8]);  acc[9]  = fmaf(coef, v.y, acc[9]);
    v = __builtin_amdgcn_cvt_pk_f32_fp8(q.z, true);  acc[10] = fmaf(coef, v.x, acc[10]); acc[11] = fmaf(coef, v.y, acc[11]);
    v = __builtin_amdgcn_cvt_pk_f32_fp8(q.w, false); acc[12] = fmaf(coef, v.x, acc[12]); acc[13] = fmaf(coef, v.y, acc[13]);
    v = __builtin_amdgcn_cvt_pk_f32_fp8(q.w, true);  acc[14] = fmaf(coef, v.x, acc[14]);
  }

  __shared__ float sm[16 * SLAB];    // 34.8 KB
  __shared__ float fin[32 * 17];     // 2.2 KB
  __shared__ int is_last;
  {
    // stride-17 b32 writes: bank = (opl*17 + j) % 32, 17 coprime 32 ->
    // lanes hit distinct banks for each j (conflict-free; was 16-way).
    float* my = &sm[g * SLAB + opl * 17];
    #pragma unroll
    for (int j = 0; j < 15; j++) my[j] = acc[j];
  }
  __syncthreads();

  // cross-group sum: 512 threads -> (px = tid>>4, component tid&15)
  {
    int px = tid >> 4;
    int cp = tid & 15;
    float s = 0.f;
    #pragma unroll
    for (int g2 = 0; g2 < 16; g2++)
      s += sm[g2 * SLAB + px * 17 + cp];
    fin[px * 17 + cp] = s;
  }
  __syncthreads();

  if (tid < 32) {
    float a[15];
    #pragma unroll
    for (int c = 0; c < 15; c++) a[c] = fin[tid * 17 + c];
    int op = blockIdx.x * 32 + tid;
    float l = 0.f;
    #pragma unroll
    for (int c = 0; c < 3; c++) {
      d_out[1 + c * OPIX + op]       = a[c];       // pred[0]
      d_out[1 + (3 + c) * OPIX + op] = a[3 + c];   // gt[0]
      float d0 = a[c] - a[3 + c];
      l += d0 * d0 + a[6 + c] * a[6 + c] + a[9 + c] * a[9 + c]
         + a[12 + c] * a[12 + c];
    }
    #pragma unroll
    for (int s = 16; s > 0; s >>= 1) l += __shfl_down(l, s);
    if (tid == 0) loss_part[blockIdx.x] = l;
  }

  // last-block-done: deterministic final loss reduction; counter self-resets.
  if (tid == 0) {
    __threadfence();                       // release loss_part[blockIdx.x]
    unsigned old = atomicAdd(cnt, 1u);
    is_last = (old == gridDim.x - 1) ? 1 : 0;
  }
  __syncthreads();
  if (is_last) {
    if (tid == 0) *cnt = 0;                // re-arm for next graph replay
    __threadfence();                       // acquire: loss_part visible
    float v = loss_part[tid];              // grid = 512 = block size
    #pragma unroll
    for (int s = 32; s > 0; s >>= 1) v += __shfl_down(v, s, 64);
    __shared__ float red[8];
    int lane = tid & 63, wid = tid >> 6;
    if (lane == 0) red[wid] = v;
    __syncthreads();
    if (tid == 0) {
      float t = 0.f;
      #pragma unroll
      for (int i = 0; i < 8; i++) t += red[i];
      d_out[0] = t * (1.0f / 98304.0f);
    }
  }
}

extern "C" void kernel_launch(void* const* d_in, const int* in_sizes, int n_in,
                              void* d_out, int out_size, void* d_ws, size_t ws_size,
                              hipStream_t stream) {
  const float* x   = (const float*)d_in[0];
  const float* y   = (const float*)d_in[1];
  const float* bs0 = (const float*)d_in[2];
  const float* bd0 = (const float*)d_in[3];
  const int*   ix0 = (const int*)  d_in[4];
  const int*   iy0 = (const int*)  d_in[5];
  const float* w0  = (const float*)d_in[6];
  const float* bs1 = (const float*)d_in[7];
  const float* bd1 = (const float*)d_in[8];
  const int*   ix1 = (const int*)  d_in[9];
  const int*   iy1 = (const int*)  d_in[10];
  const float* w1  = (const float*)d_in[11];
  float* out = (float*)d_out;

  uint4*    env       = (uint4*)d_ws;                               // 2 MB
  float*    loss_part = (float*)((char*)d_ws + (size_t)HWE * 16);   // 512 f32
  unsigned* cnt       = (unsigned*)(loss_part + 512);

  hipLaunchKernelGGL(k_repack1, dim3(HWE / 256), dim3(256), 0, stream,
                     x, y, env, cnt);
  hipLaunchKernelGGL(k_render_fused, dim3(OPIX / 32), dim3(512), 0, stream,
                     bs0, bd0, ix0, iy0, w0, bs1, bd1, ix1, iy1, w1,
                     env, out, loss_part, cnt);
}

// Round 7
// 21.116 us; speedup vs baseline: 2.6145x; 1.6048x over previous
//
#include <hip/hip_runtime.h>

#define HWE 131072   // 256*512 env pixels
#define OPIX 16384   // 128*128 output pixels

typedef float f32x2 __attribute__((ext_vector_type(2)));

// Pack per env pixel (fp8 e4m3, HW convert): [x0.rgb, y0.rgb, d1.rgb, d2.rgb,
// d3.rgb, pad] = 16 bytes. env total = 2 MB -> solidly L2-resident.
// Plain loads (round-6 lesson: nontemporal was in the +13us regression set).
__global__ __launch_bounds__(256) void k_repack1(
    const float* __restrict__ x, const float* __restrict__ y,
    uint4* __restrict__ env) {
  int px = blockIdx.x * 256 + threadIdx.x;
  float o[16];
  #pragma unroll
  for (int c = 0; c < 3; c++) {
    float x0 = x[(size_t)px * 3 + c];
    float y0 = y[(size_t)px * 3 + c];
    o[c]     = x0;
    o[3 + c] = y0;
    #pragma unroll
    for (int b = 1; b < 4; b++) {
      float xv = x[((size_t)b * HWE + px) * 3 + c];
      float yv = y[((size_t)b * HWE + px) * 3 + c];
      o[3 + b * 3 + c] = xv - yv;
    }
  }
  o[15] = 0.f;
  uint4 q;
  q.x = (unsigned)__builtin_amdgcn_cvt_pk_fp8_f32(o[2],  o[3],
        __builtin_amdgcn_cvt_pk_fp8_f32(o[0],  o[1],  0, false), true);
  q.y = (unsigned)__builtin_amdgcn_cvt_pk_fp8_f32(o[6],  o[7],
        __builtin_amdgcn_cvt_pk_fp8_f32(o[4],  o[5],  0, false), true);
  q.z = (unsigned)__builtin_amdgcn_cvt_pk_fp8_f32(o[10], o[11],
        __builtin_amdgcn_cvt_pk_fp8_f32(o[8],  o[9],  0, false), true);
  q.w = (unsigned)__builtin_amdgcn_cvt_pk_fp8_f32(o[14], o[15],
        __builtin_amdgcn_cvt_pk_fp8_f32(o[12], o[13], 0, false), true);
  env[px] = q;
}

// Fused render + cross-group reduce + outputs + per-block loss partial.
// Round-4 proven geometry: block = 512 = 16 groups x 32 px; 4 n's per thread.
// Grid = OPIX/32 = 512. No min-waves clause (round-5 spill bug).
#define SLAB 544           // 32 px * 17 floats: stride 17 coprime 32 banks
__global__ __launch_bounds__(512) void k_render_fused(
    const float* __restrict__ bs0, const float* __restrict__ bd0,
    const int* __restrict__ ix0, const int* __restrict__ iy0,
    const float* __restrict__ w0,
    const float* __restrict__ bs1, const float* __restrict__ bd1,
    const int* __restrict__ ix1, const int* __restrict__ iy1,
    const float* __restrict__ w1,
    const uint4* __restrict__ env, float* __restrict__ d_out,
    float* __restrict__ loss_part) {
  int tid = threadIdx.x;
  int g = tid >> 5;          // 0..15
  int opl = tid & 31;
  int opix = blockIdx.x * 32 + opl;

  const float* bs; const float* bd; const int* ix; const int* iy; const float* w;
  if (g < 8) { bs = bs0; bd = bd0; ix = ix0; iy = iy0; w = w0; }
  else       { bs = bs1; bd = bd1; ix = ix1; iy = iy1; w = w1; }
  int n0 = (g & 7) * 4;

  float acc[15];
  #pragma unroll
  for (int j = 0; j < 15; j++) acc[j] = 0.f;

  #pragma unroll
  for (int k = 0; k < 4; k++) {
    int n = n0 + k;
    int off = n * OPIX + opix;
    float coef = (bd[off] + 10.0f * bs[off]) * w[n];
    int gp = iy[off] * 512 + ix[off];
    uint4 q = env[gp];
    f32x2 v;
    v = __builtin_amdgcn_cvt_pk_f32_fp8(q.x, false); acc[0]  = fmaf(coef, v.x, acc[0]);  acc[1]  = fmaf(coef, v.y, acc[1]);
    v = __builtin_amdgcn_cvt_pk_f32_fp8(q.x, true);  acc[2]  = fmaf(coef, v.x, acc[2]);  acc[3]  = fmaf(coef, v.y, acc[3]);
    v = __builtin_amdgcn_cvt_pk_f32_fp8(q.y, false); acc[4]  = fmaf(coef, v.x, acc[4]);  acc[5]  = fmaf(coef, v.y, acc[5]);
    v = __builtin_amdgcn_cvt_pk_f32_fp8(q.y, true);  acc[6]  = fmaf(coef, v.x, acc[6]);  acc[7]  = fmaf(coef, v.y, acc[7]);
    v = __builtin_amdgcn_cvt_pk_f32_fp8(q.z, false); acc[8]  = fmaf(coef, v.x, acc[8]);  acc[9]  = fmaf(coef, v.y, acc[9]);
    v = __builtin_amdgcn_cvt_pk_f32_fp8(q.z, true);  acc[10] = fmaf(coef, v.x, acc[10]); acc[11] = fmaf(coef, v.y, acc[11]);
    v = __builtin_amdgcn_cvt_pk_f32_fp8(q.w, false); acc[12] = fmaf(coef, v.x, acc[12]); acc[13] = fmaf(coef, v.y, acc[13]);
    v = __builtin_amdgcn_cvt_pk_f32_fp8(q.w, true);  acc[14] = fmaf(coef, v.x, acc[14]);
  }

  __shared__ float sm[16 * SLAB];    // 34.8 KB
  __shared__ float fin[32 * 17];     // 2.2 KB
  {
    float* my = &sm[g * SLAB + opl * 17];
    #pragma unroll
    for (int j = 0; j < 15; j++) my[j] = acc[j];
  }
  __syncthreads();

  // cross-group sum: 512 threads -> (px = tid>>4, component tid&15)
  {
    int px = tid >> 4;
    int cp = tid & 15;
    float s = 0.f;
    #pragma unroll
    for (int g2 = 0; g2 < 16; g2++)
      s += sm[g2 * SLAB + px * 17 + cp];
    fin[px * 17 + cp] = s;
  }
  __syncthreads();

  if (tid < 32) {
    float a[15];
    #pragma unroll
    for (int c = 0; c < 15; c++) a[c] = fin[tid * 17 + c];
    int op = blockIdx.x * 32 + tid;
    float l = 0.f;
    #pragma unroll
    for (int c = 0; c < 3; c++) {
      d_out[1 + c * OPIX + op]       = a[c];       // pred[0]
      d_out[1 + (3 + c) * OPIX + op] = a[3 + c];   // gt[0]
      float d0 = a[c] - a[3 + c];
      l += d0 * d0 + a[6 + c] * a[6 + c] + a[9 + c] * a[9 + c]
         + a[12 + c] * a[12 + c];
    }
    #pragma unroll
    for (int s = 16; s > 0; s >>= 1) l += __shfl_down(l, s);
    if (tid == 0) loss_part[blockIdx.x] = l;
  }
}

// Deterministic final reduction of 512 block partials (no atomics).
__global__ __launch_bounds__(256) void k_loss(
    const float* __restrict__ loss_part, float* __restrict__ d_out) {
  int tid = threadIdx.x;
  float v = loss_part[tid] + loss_part[tid + 256];
  #pragma unroll
  for (int s = 32; s > 0; s >>= 1) v += __shfl_down(v, s, 64);
  __shared__ float red[4];
  int lane = tid & 63, wid = tid >> 6;
  if (lane == 0) red[wid] = v;
  __syncthreads();
  if (tid == 0)
    d_out[0] = (red[0] + red[1] + red[2] + red[3]) * (1.0f / 98304.0f);
}

extern "C" void kernel_launch(void* const* d_in, const int* in_sizes, int n_in,
                              void* d_out, int out_size, void* d_ws, size_t ws_size,
                              hipStream_t stream) {
  const float* x   = (const float*)d_in[0];
  const float* y   = (const float*)d_in[1];
  const float* bs0 = (const float*)d_in[2];
  const float* bd0 = (const float*)d_in[3];
  const int*   ix0 = (const int*)  d_in[4];
  const int*   iy0 = (const int*)  d_in[5];
  const float* w0  = (const float*)d_in[6];
  const float* bs1 = (const float*)d_in[7];
  const float* bd1 = (const float*)d_in[8];
  const int*   ix1 = (const int*)  d_in[9];
  const int*   iy1 = (const int*)  d_in[10];
  const float* w1  = (const float*)d_in[11];
  float* out = (float*)d_out;

  uint4* env       = (uint4*)d_ws;                             // 2 MB
  float* loss_part = (float*)((char*)d_ws + (size_t)HWE * 16); // 512 f32

  hipLaunchKernelGGL(k_repack1, dim3(HWE / 256), dim3(256), 0, stream,
                     x, y, env);
  hipLaunchKernelGGL(k_render_fused, dim3(OPIX / 32), dim3(512), 0, stream,
                     bs0, bd0, ix0, iy0, w0, bs1, bd1, ix1, iy1, w1,
                     env, out, loss_part);
  hipLaunchKernelGGL(k_loss, dim3(1), dim3(256), 0, stream, loss_part, out);
}